// Round 10
// baseline (1436.755 us; speedup 1.0000x reference)
//
#include <hip/hip_runtime.h>
#include <stdint.h>

#define N_NODES 50000
#define N_EDGES 12500
#define NNZV    400000
#define STEPS   20
#define DT_F    0.05f
#define SQRTDT_F 0.22360679774997896f

__device__ __forceinline__ float rdlf(float v, int l) {
  return __uint_as_float(__builtin_amdgcn_readlane(__float_as_uint(v), (unsigned)l));
}
__device__ __forceinline__ int rdli(int v, int l) {
  return (int)__builtin_amdgcn_readlane((unsigned)v, (unsigned)l);
}

// ---------------- threefry2x32 (partitionable layout) ----------------
__device__ __forceinline__ void tf2x32(uint32_t k0, uint32_t k1,
                                       uint32_t x0, uint32_t x1,
                                       uint32_t& o0, uint32_t& o1) {
  uint32_t k2 = k0 ^ k1 ^ 0x1BD11BDAu;
#define TFR(r) { x0 += x1; x1 = (x1 << (r)) | (x1 >> (32 - (r))); x1 ^= x0; }
  x0 += k0; x1 += k1;
  TFR(13) TFR(15) TFR(26) TFR(6)   x0 += k1; x1 += k2 + 1u;
  TFR(17) TFR(29) TFR(16) TFR(24)  x0 += k2; x1 += k0 + 2u;
  TFR(13) TFR(15) TFR(26) TFR(6)   x0 += k0; x1 += k1 + 3u;
  TFR(17) TFR(29) TFR(16) TFR(24)  x0 += k1; x1 += k2 + 4u;
  TFR(13) TFR(15) TFR(26) TFR(6)   x0 += k2; x1 += k0 + 5u;
#undef TFR
  o0 = x0; o1 = x1;
}

// erfinv, XLA polynomial but with hw log: w = -log((1-u)(1+u))
__device__ __forceinline__ float erfinv_fast(float x) {
  float w = -__logf((1.0f - x) * (1.0f + x));
  float p;
  if (w < 5.0f) {
    w = w - 2.5f;
    p =              2.81022636e-08f;
    p = fmaf(p, w,   3.43273939e-07f);
    p = fmaf(p, w,  -3.5233877e-06f);
    p = fmaf(p, w,  -4.39150654e-06f);
    p = fmaf(p, w,   0.00021858087f);
    p = fmaf(p, w,  -0.00125372503f);
    p = fmaf(p, w,  -0.00417768164f);
    p = fmaf(p, w,   0.246640727f);
    p = fmaf(p, w,   1.50140941f);
  } else {
    w = sqrtf(w) - 3.0f;
    p =             -0.000200214257f;
    p = fmaf(p, w,   0.000100950558f);
    p = fmaf(p, w,   0.00134934322f);
    p = fmaf(p, w,  -0.00367342844f);
    p = fmaf(p, w,   0.00573950773f);
    p = fmaf(p, w,  -0.0076224613f);
    p = fmaf(p, w,   0.00943887047f);
    p = fmaf(p, w,   1.00167406f);
    p = fmaf(p, w,   2.83297682f);
  }
  return p * x;
}

__device__ __forceinline__ float bits_to_normal(uint32_t b) {
  float f = __uint_as_float((b >> 9) | 0x3f800000u) - 1.0f;  // [0,1)
  const float lo = -0.99999994f;
  float u = fmaf(f, 2.0f, lo);
  u = fmaxf(u, lo);
  return 1.41421356237f * erfinv_fast(u);
}

// tanh via hw exp: 1 - 2/(e^{2x}+1)
__device__ __forceinline__ float fast_tanhf(float x) {
  float t = __expf(2.0f * x);
  return 1.0f - 2.0f / (t + 1.0f);
}

// ---------------- setup kernels ----------------
__global__ void k_keys(const int* __restrict__ seed, unsigned* __restrict__ keys) {
  int j = threadIdx.x;
  if (j < STEPS) {
    unsigned s = (unsigned)seed[0];
    unsigned o0, o1;
    tf2x32(0u, s, 0u, (unsigned)j, o0, o1);
    keys[2 * j] = o0; keys[2 * j + 1] = o1;
  }
}

__global__ void k_zero(int* __restrict__ p, int n) {
  int i = blockIdx.x * 256 + threadIdx.x;
  if (i < n) p[i] = 0;
}

__global__ void k_hist(const int* __restrict__ nidx, const int* __restrict__ eidx,
                       int* __restrict__ ecnt, int* __restrict__ ncnt) {
  int i = blockIdx.x * 256 + threadIdx.x;
  if (i < NNZV) {
    atomicAdd(&ecnt[eidx[i]], 1);
    atomicAdd(&ncnt[nidx[i]], 1);
  }
}

// ---- hierarchical exclusive scan over cnt[len]: 1024 elems per block ----
__global__ __launch_bounds__(256) void k_reduce(const int* __restrict__ cnt, int len,
                                                int* __restrict__ bsum) {
  __shared__ int sh[256];
  int b = blockIdx.x, tid = threadIdx.x;
  int base = b * 1024 + tid * 4;
  int s = 0;
#pragma unroll
  for (int j = 0; j < 4; ++j) {
    int i = base + j;
    if (i < len) s += cnt[i];
  }
  sh[tid] = s;
  __syncthreads();
  for (int off = 128; off > 0; off >>= 1) {
    if (tid < off) sh[tid] += sh[tid + off];
    __syncthreads();
  }
  if (tid == 0) bsum[b] = sh[0];
}

__global__ __launch_bounds__(256) void k_scanb(int* __restrict__ bsum, int nb) {
  __shared__ int sh[256];
  int tid = threadIdx.x;
  int v = (tid < nb) ? bsum[tid] : 0;
  sh[tid] = v;
  __syncthreads();
  for (int off = 1; off < 256; off <<= 1) {
    int t = (tid >= off) ? sh[tid - off] : 0;
    __syncthreads();
    sh[tid] += t;
    __syncthreads();
  }
  if (tid < nb) bsum[tid] = sh[tid] - v;   // exclusive
}

__global__ __launch_bounds__(256) void k_scatter(const int* __restrict__ cnt,
                                                 const int* __restrict__ bsum, int len,
                                                 int* __restrict__ start,
                                                 int* __restrict__ fill,
                                                 float* __restrict__ dinv) {
  __shared__ int sh[256];
  int b = blockIdx.x, tid = threadIdx.x;
  int base = b * 1024 + tid * 4;
  int c[4], lex[4];
  int s = 0;
#pragma unroll
  for (int j = 0; j < 4; ++j) {
    int i = base + j;
    c[j] = (i < len) ? cnt[i] : 0;
    lex[j] = s;
    s += c[j];
  }
  sh[tid] = s;
  __syncthreads();
  for (int off = 1; off < 256; off <<= 1) {
    int t = (tid >= off) ? sh[tid - off] : 0;
    __syncthreads();
    sh[tid] += t;
    __syncthreads();
  }
  int off0 = bsum[b] + sh[tid] - s;
#pragma unroll
  for (int j = 0; j < 4; ++j) {
    int i = base + j;
    if (i < len) {
      start[i] = off0 + lex[j];
      fill[i] = 0;
      dinv[i] = 1.0f / (float)(c[j] > 1 ? c[j] : 1);
    }
  }
}

__global__ void k_fill(const int* __restrict__ nidx, const int* __restrict__ eidx,
                       const int* __restrict__ estart, const int* __restrict__ nstart,
                       int* __restrict__ efill, int* __restrict__ nfill,
                       int* __restrict__ emem, int* __restrict__ nmem) {
  int i = blockIdx.x * 256 + threadIdx.x;
  if (i < NNZV) {
    int e = eidx[i], n = nidx[i];
    int pe = atomicAdd(&efill[e], 1);
    emem[estart[e] + pe] = n;
    int pn = atomicAdd(&nfill[n], 1);
    nmem[nstart[n] + pn] = e;
  }
}

// stage a 64x64 row-major matrix into LDS, XOR-swizzled (write & read 2-way = free)
__device__ __forceinline__ void stage_swz(const float* __restrict__ w,
                                          float* __restrict__ lds, int tid) {
  for (int idx = tid; idx < 4096; idx += 256) {
    int j = idx >> 6, k = idx & 63;
    lds[k * 64 + (j ^ k)] = w[idx];
  }
}

// 16-wide gather-sum over a CSR segment: 16 row loads in flight per group
__device__ __forceinline__ float seg_gather_sum(const float* __restrict__ rows,
                                                const int* __restrict__ mem,
                                                int start, int deg, int lane) {
  float acc0 = 0.f, acc1 = 0.f, acc2 = 0.f, acc3 = 0.f;
  for (int base = 0; base < deg; base += 64) {
    int rem = min(64, deg - base);
    int ids = (lane < rem) ? mem[start + base + lane] : 0;
    int i = 0;
    for (; i + 16 <= rem; i += 16) {
      int j0  = rdli(ids, i),      j1  = rdli(ids, i + 1);
      int j2  = rdli(ids, i + 2),  j3  = rdli(ids, i + 3);
      int j4  = rdli(ids, i + 4),  j5  = rdli(ids, i + 5);
      int j6  = rdli(ids, i + 6),  j7  = rdli(ids, i + 7);
      int j8  = rdli(ids, i + 8),  j9  = rdli(ids, i + 9);
      int j10 = rdli(ids, i + 10), j11 = rdli(ids, i + 11);
      int j12 = rdli(ids, i + 12), j13 = rdli(ids, i + 13);
      int j14 = rdli(ids, i + 14), j15 = rdli(ids, i + 15);
      float v0  = rows[(size_t)j0  * 64 + lane], v1  = rows[(size_t)j1  * 64 + lane];
      float v2  = rows[(size_t)j2  * 64 + lane], v3  = rows[(size_t)j3  * 64 + lane];
      float v4  = rows[(size_t)j4  * 64 + lane], v5  = rows[(size_t)j5  * 64 + lane];
      float v6  = rows[(size_t)j6  * 64 + lane], v7  = rows[(size_t)j7  * 64 + lane];
      float v8  = rows[(size_t)j8  * 64 + lane], v9  = rows[(size_t)j9  * 64 + lane];
      float v10 = rows[(size_t)j10 * 64 + lane], v11 = rows[(size_t)j11 * 64 + lane];
      float v12 = rows[(size_t)j12 * 64 + lane], v13 = rows[(size_t)j13 * 64 + lane];
      float v14 = rows[(size_t)j14 * 64 + lane], v15 = rows[(size_t)j15 * 64 + lane];
      acc0 += (v0 + v1) + (v2 + v3);
      acc1 += (v4 + v5) + (v6 + v7);
      acc2 += (v8 + v9) + (v10 + v11);
      acc3 += (v12 + v13) + (v14 + v15);
    }
    for (; i + 4 <= rem; i += 4) {
      int j0 = rdli(ids, i),     j1 = rdli(ids, i + 1);
      int j2 = rdli(ids, i + 2), j3 = rdli(ids, i + 3);
      float v0 = rows[(size_t)j0 * 64 + lane], v1 = rows[(size_t)j1 * 64 + lane];
      float v2 = rows[(size_t)j2 * 64 + lane], v3 = rows[(size_t)j3 * 64 + lane];
      acc0 += (v0 + v1) + (v2 + v3);
    }
    for (; i < rem; ++i) acc0 += rows[(size_t)rdli(ids, i) * 64 + lane];
  }
  return (acc0 + acc1) + (acc2 + acc3);
}

// ---------------- encoder: y = relu(x@w1^T+b1)@w2^T + b2 ----------------
__global__ __launch_bounds__(256) void k_encoder(
    const float* __restrict__ x, const float* __restrict__ w1,
    const float* __restrict__ b1, const float* __restrict__ w2,
    const float* __restrict__ b2, float* __restrict__ y) {
  __shared__ float lw1[4096], lw2[4096];
  int tid = threadIdx.x;
  stage_swz(w1, lw1, tid);
  stage_swz(w2, lw2, tid);
  __syncthreads();
  int lane = tid & 63, wave = tid >> 6;
  float w1r[64], w2r[64];
#pragma unroll
  for (int k = 0; k < 64; ++k) {
    w1r[k] = lw1[k * 64 + (lane ^ k)];
    w2r[k] = lw2[k * 64 + (lane ^ k)];
  }
  float b1v = b1[lane], b2v = b2[lane];
  int gw = blockIdx.x * 4 + wave, nw = gridDim.x * 4;
  for (int n = gw; n < N_NODES; n += nw) {
    float xv = x[(size_t)n * 64 + lane];
    float a0 = 0.f, a1 = 0.f, a2 = 0.f, a3 = 0.f;
#pragma unroll
    for (int k = 0; k < 64; k += 4) {
      a0 = fmaf(rdlf(xv, k),     w1r[k],     a0);
      a1 = fmaf(rdlf(xv, k + 1), w1r[k + 1], a1);
      a2 = fmaf(rdlf(xv, k + 2), w1r[k + 2], a2);
      a3 = fmaf(rdlf(xv, k + 3), w1r[k + 3], a3);
    }
    float h = fmaxf((a0 + a1) + (a2 + a3) + b1v, 0.f);
    a0 = a1 = a2 = a3 = 0.f;
#pragma unroll
    for (int k = 0; k < 64; k += 4) {
      a0 = fmaf(rdlf(h, k),     w2r[k],     a0);
      a1 = fmaf(rdlf(h, k + 1), w2r[k + 1], a1);
      a2 = fmaf(rdlf(h, k + 2), w2r[k + 2], a2);
      a3 = fmaf(rdlf(h, k + 3), w2r[k + 3], a3);
    }
    y[(size_t)n * 64 + lane] = (a0 + a1) + (a2 + a3) + b2v;
  }
}

// ---------------- per step: edge aggregation + per-EDGE matvec ----------------
__global__ __launch_bounds__(256) void k_edge(
    const float* __restrict__ y, float* __restrict__ e,
    const int* __restrict__ estart, const int* __restrict__ ecnt,
    const int* __restrict__ emem, const float* __restrict__ edinv,
    const float* __restrict__ cw) {
  __shared__ float lcw[4096];
  int tid = threadIdx.x;
  stage_swz(cw, lcw, tid);
  __syncthreads();
  int lane = tid & 63, wave = tid >> 6;
  float cwr[64];
#pragma unroll
  for (int k = 0; k < 64; ++k) cwr[k] = lcw[k * 64 + (lane ^ k)];
  int gw = blockIdx.x * 4 + wave, nw = gridDim.x * 4;
  for (int ed = gw; ed < N_EDGES; ed += nw) {
    int start = estart[ed], deg = ecnt[ed];
    float acc = seg_gather_sum(y, emem, start, deg, lane);
    float a0 = 0.f, a1 = 0.f, a2 = 0.f, a3 = 0.f;
#pragma unroll
    for (int k = 0; k < 64; k += 4) {
      a0 = fmaf(rdlf(acc, k),     cwr[k],     a0);
      a1 = fmaf(rdlf(acc, k + 1), cwr[k + 1], a1);
      a2 = fmaf(rdlf(acc, k + 2), cwr[k + 2], a2);
      a3 = fmaf(rdlf(acc, k + 3), cwr[k + 3], a3);
    }
    e[(size_t)ed * 64 + lane] = ((a0 + a1) + (a2 + a3)) * edinv[ed];
  }
}

// ---------------- per step: node aggregation + tanh + noise + y update ----------------
__global__ __launch_bounds__(256) void k_node(
    const float* __restrict__ e, float* __restrict__ y,
    const int* __restrict__ nstart, const int* __restrict__ ncnt,
    const int* __restrict__ nmem, const float* __restrict__ ndinv,
    const float* __restrict__ cb, const float* __restrict__ sigma,
    const unsigned* __restrict__ keys, int s) {
  int tid = threadIdx.x;
  int lane = tid & 63, wave = tid >> 6;
  float cbv = cb[lane];
  float sgv = sigma[lane] * SQRTDT_F;
  unsigned ka = keys[2 * s], kb = keys[2 * s + 1];
  int gw = blockIdx.x * 4 + wave, nw = gridDim.x * 4;
  for (int n = gw; n < N_NODES; n += nw) {
    float yv = y[(size_t)n * 64 + lane];     // independent load, issued early
    float acc = seg_gather_sum(e, nmem, nstart[n], ncnt[n], lane);
    uint32_t r0, r1;
    tf2x32(ka, kb, 0u, (unsigned)(n * 64 + lane), r0, r1);
    float dw = bits_to_normal(r0 ^ r1);
    yv = fmaf(fast_tanhf(fmaf(acc, ndinv[n], cbv)), DT_F, fmaf(sgv, dw, yv));
    y[(size_t)n * 64 + lane] = yv;
  }
}

// ---------------- decoder ----------------
__global__ __launch_bounds__(256) void k_decoder(
    const float* __restrict__ y, const float* __restrict__ w1,
    const float* __restrict__ b1, const float* __restrict__ w2,
    const float* __restrict__ b2, float* __restrict__ out) {
  __shared__ float lw1[4096], lw2[4096];
  int tid = threadIdx.x;
  stage_swz(w1, lw1, tid);
  stage_swz(w2, lw2, tid);
  __syncthreads();
  int lane = tid & 63, wave = tid >> 6;
  float w1r[64], w2r[64];
#pragma unroll
  for (int k = 0; k < 64; ++k) {
    w1r[k] = lw1[k * 64 + (lane ^ k)];
    w2r[k] = lw2[k * 64 + (lane ^ k)];
  }
  float b1v = b1[lane], b2v = b2[lane];
  int gw = blockIdx.x * 4 + wave, nw = gridDim.x * 4;
  for (int n = gw; n < N_NODES; n += nw) {
    float xv = y[(size_t)n * 64 + lane];
    float a0 = 0.f, a1 = 0.f, a2 = 0.f, a3 = 0.f;
#pragma unroll
    for (int k = 0; k < 64; k += 4) {
      a0 = fmaf(rdlf(xv, k),     w1r[k],     a0);
      a1 = fmaf(rdlf(xv, k + 1), w1r[k + 1], a1);
      a2 = fmaf(rdlf(xv, k + 2), w1r[k + 2], a2);
      a3 = fmaf(rdlf(xv, k + 3), w1r[k + 3], a3);
    }
    float h = fmaxf((a0 + a1) + (a2 + a3) + b1v, 0.f);
    a0 = a1 = a2 = a3 = 0.f;
#pragma unroll
    for (int k = 0; k < 64; k += 4) {
      a0 = fmaf(rdlf(h, k),     w2r[k],     a0);
      a1 = fmaf(rdlf(h, k + 1), w2r[k + 1], a1);
      a2 = fmaf(rdlf(h, k + 2), w2r[k + 2], a2);
      a3 = fmaf(rdlf(h, k + 3), w2r[k + 3], a3);
    }
    out[(size_t)n * 64 + lane] = (a0 + a1) + (a2 + a3) + b2v;
  }
}

extern "C" void kernel_launch(void* const* d_in, const int* in_sizes, int n_in,
                              void* d_out, int out_size, void* d_ws, size_t ws_size,
                              hipStream_t stream) {
  (void)in_sizes; (void)n_in; (void)out_size; (void)ws_size;
  const float* x      = (const float*)d_in[0];
  const float* enc_w1 = (const float*)d_in[1];
  const float* enc_b1 = (const float*)d_in[2];
  const float* enc_w2 = (const float*)d_in[3];
  const float* enc_b2 = (const float*)d_in[4];
  const float* conv_w = (const float*)d_in[5];
  const float* conv_b = (const float*)d_in[6];
  const float* sigma  = (const float*)d_in[7];
  const float* dec_w1 = (const float*)d_in[8];
  const float* dec_b1 = (const float*)d_in[9];
  const float* dec_w2 = (const float*)d_in[10];
  const float* dec_b2 = (const float*)d_in[11];
  const int* node_idx = (const int*)d_in[12];
  const int* edge_idx = (const int*)d_in[13];
  const int* seed     = (const int*)d_in[14];

  char* wsb = (char*)d_ws;
  size_t off = 0;
  auto alloc = [&](size_t bytes) -> void* {
    void* p = wsb + off;
    off = (off + bytes + 255) & ~(size_t)255;
    return p;
  };
  float* y        = (float*)alloc((size_t)N_NODES * 64 * 4);
  float* e        = (float*)alloc((size_t)N_EDGES * 64 * 4);
  int* edge_cnt   = (int*)alloc((size_t)N_EDGES * 4);
  int* node_cnt   = (int*)alloc((size_t)N_NODES * 4);
  int* edge_start = (int*)alloc((size_t)N_EDGES * 4);
  int* node_start = (int*)alloc((size_t)N_NODES * 4);
  int* edge_fill  = (int*)alloc((size_t)N_EDGES * 4);
  int* node_fill  = (int*)alloc((size_t)N_NODES * 4);
  int* edge_mem   = (int*)alloc((size_t)NNZV * 4);
  int* node_mem   = (int*)alloc((size_t)NNZV * 4);
  float* edinv    = (float*)alloc((size_t)N_EDGES * 4);
  float* ndinv    = (float*)alloc((size_t)N_NODES * 4);
  unsigned* keys  = (unsigned*)alloc(2 * STEPS * 4);
  int* ebsum      = (int*)alloc(256 * 4);
  int* nbsum      = (int*)alloc(256 * 4);

  const int EB = (N_EDGES + 1023) / 1024;   // 13
  const int NB = (N_NODES + 1023) / 1024;   // 49

  dim3 b256(256);
  hipLaunchKernelGGL(k_keys, dim3(1), dim3(64), 0, stream, seed, keys);
  hipLaunchKernelGGL(k_zero, dim3((N_EDGES + 255) / 256), b256, 0, stream, edge_cnt, N_EDGES);
  hipLaunchKernelGGL(k_zero, dim3((N_NODES + 255) / 256), b256, 0, stream, node_cnt, N_NODES);
  hipLaunchKernelGGL(k_hist, dim3((NNZV + 255) / 256), b256, 0, stream,
                     node_idx, edge_idx, edge_cnt, node_cnt);
  hipLaunchKernelGGL(k_reduce, dim3(EB), b256, 0, stream, edge_cnt, N_EDGES, ebsum);
  hipLaunchKernelGGL(k_reduce, dim3(NB), b256, 0, stream, node_cnt, N_NODES, nbsum);
  hipLaunchKernelGGL(k_scanb, dim3(1), b256, 0, stream, ebsum, EB);
  hipLaunchKernelGGL(k_scanb, dim3(1), b256, 0, stream, nbsum, NB);
  hipLaunchKernelGGL(k_scatter, dim3(EB), b256, 0, stream,
                     edge_cnt, ebsum, N_EDGES, edge_start, edge_fill, edinv);
  hipLaunchKernelGGL(k_scatter, dim3(NB), b256, 0, stream,
                     node_cnt, nbsum, N_NODES, node_start, node_fill, ndinv);
  hipLaunchKernelGGL(k_fill, dim3((NNZV + 255) / 256), b256, 0, stream,
                     node_idx, edge_idx, edge_start, node_start,
                     edge_fill, node_fill, edge_mem, node_mem);
  hipLaunchKernelGGL(k_encoder, dim3(1024), b256, 0, stream,
                     x, enc_w1, enc_b1, enc_w2, enc_b2, y);
  for (int s = 0; s < STEPS; ++s) {
    hipLaunchKernelGGL(k_edge, dim3(1024), b256, 0, stream,
                       y, e, edge_start, edge_cnt, edge_mem, edinv, conv_w);
    hipLaunchKernelGGL(k_node, dim3(2048), b256, 0, stream,
                       e, y, node_start, node_cnt, node_mem, ndinv,
                       conv_b, sigma, keys, s);
  }
  hipLaunchKernelGGL(k_decoder, dim3(1024), b256, 0, stream,
                     y, dec_w1, dec_b1, dec_w2, dec_b2, (float*)d_out);
}

// Round 11
// 1079.055 us; speedup vs baseline: 1.3315x; 1.3315x over previous
//
#include <hip/hip_runtime.h>
#include <stdint.h>

#define N_NODES 50000
#define N_EDGES 12500
#define NNZV    400000
#define STEPS   20
#define DT_F    0.05f
#define SQRTDT_F 0.22360679774997896f

__device__ __forceinline__ float rdlf(float v, int l) {
  return __uint_as_float(__builtin_amdgcn_readlane(__float_as_uint(v), (unsigned)l));
}
__device__ __forceinline__ int rfl(int v) {
  return (int)__builtin_amdgcn_readfirstlane((unsigned)v);
}

// ---------------- threefry2x32 (partitionable layout) ----------------
__device__ __forceinline__ void tf2x32(uint32_t k0, uint32_t k1,
                                       uint32_t x0, uint32_t x1,
                                       uint32_t& o0, uint32_t& o1) {
  uint32_t k2 = k0 ^ k1 ^ 0x1BD11BDAu;
#define TFR(r) { x0 += x1; x1 = (x1 << (r)) | (x1 >> (32 - (r))); x1 ^= x0; }
  x0 += k0; x1 += k1;
  TFR(13) TFR(15) TFR(26) TFR(6)   x0 += k1; x1 += k2 + 1u;
  TFR(17) TFR(29) TFR(16) TFR(24)  x0 += k2; x1 += k0 + 2u;
  TFR(13) TFR(15) TFR(26) TFR(6)   x0 += k0; x1 += k1 + 3u;
  TFR(17) TFR(29) TFR(16) TFR(24)  x0 += k1; x1 += k2 + 4u;
  TFR(13) TFR(15) TFR(26) TFR(6)   x0 += k2; x1 += k0 + 5u;
#undef TFR
  o0 = x0; o1 = x1;
}

// erfinv, XLA polynomial but with hw log: w = -log((1-u)(1+u))
__device__ __forceinline__ float erfinv_fast(float x) {
  float w = -__logf((1.0f - x) * (1.0f + x));
  float p;
  if (w < 5.0f) {
    w = w - 2.5f;
    p =              2.81022636e-08f;
    p = fmaf(p, w,   3.43273939e-07f);
    p = fmaf(p, w,  -3.5233877e-06f);
    p = fmaf(p, w,  -4.39150654e-06f);
    p = fmaf(p, w,   0.00021858087f);
    p = fmaf(p, w,  -0.00125372503f);
    p = fmaf(p, w,  -0.00417768164f);
    p = fmaf(p, w,   0.246640727f);
    p = fmaf(p, w,   1.50140941f);
  } else {
    w = sqrtf(w) - 3.0f;
    p =             -0.000200214257f;
    p = fmaf(p, w,   0.000100950558f);
    p = fmaf(p, w,   0.00134934322f);
    p = fmaf(p, w,  -0.00367342844f);
    p = fmaf(p, w,   0.00573950773f);
    p = fmaf(p, w,  -0.0076224613f);
    p = fmaf(p, w,   0.00943887047f);
    p = fmaf(p, w,   1.00167406f);
    p = fmaf(p, w,   2.83297682f);
  }
  return p * x;
}

__device__ __forceinline__ float bits_to_normal(uint32_t b) {
  float f = __uint_as_float((b >> 9) | 0x3f800000u) - 1.0f;  // [0,1)
  const float lo = -0.99999994f;
  float u = fmaf(f, 2.0f, lo);
  u = fmaxf(u, lo);
  return 1.41421356237f * erfinv_fast(u);
}

// tanh via hw exp: 1 - 2/(e^{2x}+1)
__device__ __forceinline__ float fast_tanhf(float x) {
  float t = __expf(2.0f * x);
  return 1.0f - 2.0f / (t + 1.0f);
}

// ---------------- setup kernels ----------------
__global__ void k_keys(const int* __restrict__ seed, unsigned* __restrict__ keys) {
  int j = threadIdx.x;
  if (j < STEPS) {
    unsigned s = (unsigned)seed[0];
    unsigned o0, o1;
    tf2x32(0u, s, 0u, (unsigned)j, o0, o1);
    keys[2 * j] = o0; keys[2 * j + 1] = o1;
  }
}

__global__ void k_zero(int* __restrict__ p, int n) {
  int i = blockIdx.x * 256 + threadIdx.x;
  if (i < n) p[i] = 0;
}

__global__ void k_hist(const int* __restrict__ nidx, const int* __restrict__ eidx,
                       int* __restrict__ ecnt, int* __restrict__ ncnt) {
  int i = blockIdx.x * 256 + threadIdx.x;
  if (i < NNZV) {
    atomicAdd(&ecnt[eidx[i]], 1);
    atomicAdd(&ncnt[nidx[i]], 1);
  }
}

// ---- hierarchical exclusive scan over cnt[len]: 1024 elems per block ----
__global__ __launch_bounds__(256) void k_reduce(const int* __restrict__ cnt, int len,
                                                int* __restrict__ bsum) {
  __shared__ int sh[256];
  int b = blockIdx.x, tid = threadIdx.x;
  int base = b * 1024 + tid * 4;
  int s = 0;
#pragma unroll
  for (int j = 0; j < 4; ++j) {
    int i = base + j;
    if (i < len) s += cnt[i];
  }
  sh[tid] = s;
  __syncthreads();
  for (int off = 128; off > 0; off >>= 1) {
    if (tid < off) sh[tid] += sh[tid + off];
    __syncthreads();
  }
  if (tid == 0) bsum[b] = sh[0];
}

__global__ __launch_bounds__(256) void k_scanb(int* __restrict__ bsum, int nb) {
  __shared__ int sh[256];
  int tid = threadIdx.x;
  int v = (tid < nb) ? bsum[tid] : 0;
  sh[tid] = v;
  __syncthreads();
  for (int off = 1; off < 256; off <<= 1) {
    int t = (tid >= off) ? sh[tid - off] : 0;
    __syncthreads();
    sh[tid] += t;
    __syncthreads();
  }
  if (tid < nb) bsum[tid] = sh[tid] - v;   // exclusive
}

__global__ __launch_bounds__(256) void k_scatter(const int* __restrict__ cnt,
                                                 const int* __restrict__ bsum, int len,
                                                 int* __restrict__ start,
                                                 int* __restrict__ fill,
                                                 float* __restrict__ dinv) {
  __shared__ int sh[256];
  int b = blockIdx.x, tid = threadIdx.x;
  int base = b * 1024 + tid * 4;
  int c[4], lex[4];
  int s = 0;
#pragma unroll
  for (int j = 0; j < 4; ++j) {
    int i = base + j;
    c[j] = (i < len) ? cnt[i] : 0;
    lex[j] = s;
    s += c[j];
  }
  sh[tid] = s;
  __syncthreads();
  for (int off = 1; off < 256; off <<= 1) {
    int t = (tid >= off) ? sh[tid - off] : 0;
    __syncthreads();
    sh[tid] += t;
    __syncthreads();
  }
  int off0 = bsum[b] + sh[tid] - s;
#pragma unroll
  for (int j = 0; j < 4; ++j) {
    int i = base + j;
    if (i < len) {
      start[i] = off0 + lex[j];
      fill[i] = 0;
      dinv[i] = 1.0f / (float)(c[j] > 1 ? c[j] : 1);
    }
  }
}

__global__ void k_fill(const int* __restrict__ nidx, const int* __restrict__ eidx,
                       const int* __restrict__ estart, const int* __restrict__ nstart,
                       int* __restrict__ efill, int* __restrict__ nfill,
                       int* __restrict__ emem, int* __restrict__ nmem) {
  int i = blockIdx.x * 256 + threadIdx.x;
  if (i < NNZV) {
    int e = eidx[i], n = nidx[i];
    int pe = atomicAdd(&efill[e], 1);
    emem[estart[e] + pe] = n;
    int pn = atomicAdd(&nfill[n], 1);
    nmem[nstart[n] + pn] = e;
  }
}

// stage a 64x64 row-major matrix into LDS, XOR-swizzled (write & read 2-way = free)
__device__ __forceinline__ void stage_swz(const float* __restrict__ w,
                                          float* __restrict__ lds, int tid) {
  for (int idx = tid; idx < 4096; idx += 256) {
    int j = idx >> 6, k = idx & 63;
    lds[k * 64 + (j ^ k)] = w[idx];
  }
}

// scalar-uniform gather-sum: segment ids loaded via uniform (SGPR) loads,
// row loads use scalar base + lane offset. 8 row loads in flight per group.
__device__ __forceinline__ float seg_gather_scalar(const float* __restrict__ rows,
                                                   const int* __restrict__ mem,
                                                   int st, int deg, int lane) {
  float a0 = 0.f, a1 = 0.f, a2 = 0.f, a3 = 0.f;
  int i = 0;
  for (; i + 8 <= deg; i += 8) {
    int d0 = mem[st + i],     d1 = mem[st + i + 1];
    int d2 = mem[st + i + 2], d3 = mem[st + i + 3];
    int d4 = mem[st + i + 4], d5 = mem[st + i + 5];
    int d6 = mem[st + i + 6], d7 = mem[st + i + 7];
    float v0 = rows[(size_t)d0 * 64 + lane], v1 = rows[(size_t)d1 * 64 + lane];
    float v2 = rows[(size_t)d2 * 64 + lane], v3 = rows[(size_t)d3 * 64 + lane];
    float v4 = rows[(size_t)d4 * 64 + lane], v5 = rows[(size_t)d5 * 64 + lane];
    float v6 = rows[(size_t)d6 * 64 + lane], v7 = rows[(size_t)d7 * 64 + lane];
    a0 += v0 + v1; a1 += v2 + v3; a2 += v4 + v5; a3 += v6 + v7;
  }
  for (; i < deg; ++i)
    a0 += rows[(size_t)mem[st + i] * 64 + lane];
  return (a0 + a1) + (a2 + a3);
}

// ---------------- encoder: y = relu(x@w1^T+b1)@w2^T + b2 ----------------
__global__ __launch_bounds__(256) void k_encoder(
    const float* __restrict__ x, const float* __restrict__ w1,
    const float* __restrict__ b1, const float* __restrict__ w2,
    const float* __restrict__ b2, float* __restrict__ y) {
  __shared__ float lw1[4096], lw2[4096];
  int tid = threadIdx.x;
  stage_swz(w1, lw1, tid);
  stage_swz(w2, lw2, tid);
  __syncthreads();
  int lane = tid & 63, wave = tid >> 6;
  float w1r[64], w2r[64];
#pragma unroll
  for (int k = 0; k < 64; ++k) {
    w1r[k] = lw1[k * 64 + (lane ^ k)];
    w2r[k] = lw2[k * 64 + (lane ^ k)];
  }
  float b1v = b1[lane], b2v = b2[lane];
  int gw = blockIdx.x * 4 + wave, nw = gridDim.x * 4;
  for (int n = gw; n < N_NODES; n += nw) {
    float xv = x[(size_t)n * 64 + lane];
    float a0 = 0.f, a1 = 0.f, a2 = 0.f, a3 = 0.f;
#pragma unroll
    for (int k = 0; k < 64; k += 4) {
      a0 = fmaf(rdlf(xv, k),     w1r[k],     a0);
      a1 = fmaf(rdlf(xv, k + 1), w1r[k + 1], a1);
      a2 = fmaf(rdlf(xv, k + 2), w1r[k + 2], a2);
      a3 = fmaf(rdlf(xv, k + 3), w1r[k + 3], a3);
    }
    float h = fmaxf((a0 + a1) + (a2 + a3) + b1v, 0.f);
    a0 = a1 = a2 = a3 = 0.f;
#pragma unroll
    for (int k = 0; k < 64; k += 4) {
      a0 = fmaf(rdlf(h, k),     w2r[k],     a0);
      a1 = fmaf(rdlf(h, k + 1), w2r[k + 1], a1);
      a2 = fmaf(rdlf(h, k + 2), w2r[k + 2], a2);
      a3 = fmaf(rdlf(h, k + 3), w2r[k + 3], a3);
    }
    y[(size_t)n * 64 + lane] = (a0 + a1) + (a2 + a3) + b2v;
  }
}

// ---------------- per step: edge aggregation + per-EDGE matvec ----------------
__global__ __launch_bounds__(256) void k_edge(
    const float* __restrict__ y, float* __restrict__ e,
    const int* __restrict__ estart, const int* __restrict__ ecnt,
    const int* __restrict__ emem, const float* __restrict__ edinv,
    const float* __restrict__ cw) {
  __shared__ float lcw[4096];
  int tid = threadIdx.x;
  stage_swz(cw, lcw, tid);
  __syncthreads();
  int lane = tid & 63, wave = tid >> 6;
  int gw = blockIdx.x * 4 + wave, nw = gridDim.x * 4;
  for (int ed = gw; ed < N_EDGES; ed += nw) {
    int edu = rfl(ed);                       // wave-uniform -> scalar loads below
    int st  = estart[edu], deg = ecnt[edu];
    float div = edinv[edu];
    float acc = seg_gather_scalar(y, emem, st, deg, lane);
    float a0 = 0.f, a1 = 0.f, a2 = 0.f, a3 = 0.f;
#pragma unroll
    for (int k = 0; k < 64; k += 4) {
      a0 = fmaf(rdlf(acc, k),     lcw[k * 64 + (lane ^ k)],             a0);
      a1 = fmaf(rdlf(acc, k + 1), lcw[(k + 1) * 64 + (lane ^ (k + 1))], a1);
      a2 = fmaf(rdlf(acc, k + 2), lcw[(k + 2) * 64 + (lane ^ (k + 2))], a2);
      a3 = fmaf(rdlf(acc, k + 3), lcw[(k + 3) * 64 + (lane ^ (k + 3))], a3);
    }
    e[(size_t)edu * 64 + lane] = ((a0 + a1) + (a2 + a3)) * div;
  }
}

// ---------------- per step: node aggregation + tanh + noise + y update ----------------
__global__ __launch_bounds__(256) void k_node(
    const float* __restrict__ e, float* __restrict__ y,
    const int* __restrict__ nstart, const int* __restrict__ ncnt,
    const int* __restrict__ nmem, const float* __restrict__ ndinv,
    const float* __restrict__ cb, const float* __restrict__ sigma,
    const unsigned* __restrict__ keys, int s) {
  int tid = threadIdx.x;
  int lane = tid & 63, wave = tid >> 6;
  float cbv = cb[lane];
  float sgv = sigma[lane] * SQRTDT_F;
  unsigned ka = keys[2 * s], kb = keys[2 * s + 1];
  int gw = blockIdx.x * 4 + wave, nw = gridDim.x * 4;
  for (int n = gw; n < N_NODES; n += nw) {
    int nu = rfl(n);                         // wave-uniform -> scalar loads below
    int st = nstart[nu], deg = ncnt[nu];
    float dinv = ndinv[nu];
    float yv = y[(size_t)nu * 64 + lane];    // independent load, issued early
    float acc = seg_gather_scalar(e, nmem, st, deg, lane);
    uint32_t r0, r1;
    tf2x32(ka, kb, 0u, (unsigned)(nu * 64 + lane), r0, r1);
    float dw = bits_to_normal(r0 ^ r1);
    yv = fmaf(fast_tanhf(fmaf(acc, dinv, cbv)), DT_F, fmaf(sgv, dw, yv));
    y[(size_t)nu * 64 + lane] = yv;
  }
}

// ---------------- decoder ----------------
__global__ __launch_bounds__(256) void k_decoder(
    const float* __restrict__ y, const float* __restrict__ w1,
    const float* __restrict__ b1, const float* __restrict__ w2,
    const float* __restrict__ b2, float* __restrict__ out) {
  __shared__ float lw1[4096], lw2[4096];
  int tid = threadIdx.x;
  stage_swz(w1, lw1, tid);
  stage_swz(w2, lw2, tid);
  __syncthreads();
  int lane = tid & 63, wave = tid >> 6;
  float w1r[64], w2r[64];
#pragma unroll
  for (int k = 0; k < 64; ++k) {
    w1r[k] = lw1[k * 64 + (lane ^ k)];
    w2r[k] = lw2[k * 64 + (lane ^ k)];
  }
  float b1v = b1[lane], b2v = b2[lane];
  int gw = blockIdx.x * 4 + wave, nw = gridDim.x * 4;
  for (int n = gw; n < N_NODES; n += nw) {
    float xv = y[(size_t)n * 64 + lane];
    float a0 = 0.f, a1 = 0.f, a2 = 0.f, a3 = 0.f;
#pragma unroll
    for (int k = 0; k < 64; k += 4) {
      a0 = fmaf(rdlf(xv, k),     w1r[k],     a0);
      a1 = fmaf(rdlf(xv, k + 1), w1r[k + 1], a1);
      a2 = fmaf(rdlf(xv, k + 2), w1r[k + 2], a2);
      a3 = fmaf(rdlf(xv, k + 3), w1r[k + 3], a3);
    }
    float h = fmaxf((a0 + a1) + (a2 + a3) + b1v, 0.f);
    a0 = a1 = a2 = a3 = 0.f;
#pragma unroll
    for (int k = 0; k < 64; k += 4) {
      a0 = fmaf(rdlf(h, k),     w2r[k],     a0);
      a1 = fmaf(rdlf(h, k + 1), w2r[k + 1], a1);
      a2 = fmaf(rdlf(h, k + 2), w2r[k + 2], a2);
      a3 = fmaf(rdlf(h, k + 3), w2r[k + 3], a3);
    }
    out[(size_t)n * 64 + lane] = (a0 + a1) + (a2 + a3) + b2v;
  }
}

extern "C" void kernel_launch(void* const* d_in, const int* in_sizes, int n_in,
                              void* d_out, int out_size, void* d_ws, size_t ws_size,
                              hipStream_t stream) {
  (void)in_sizes; (void)n_in; (void)out_size; (void)ws_size;
  const float* x      = (const float*)d_in[0];
  const float* enc_w1 = (const float*)d_in[1];
  const float* enc_b1 = (const float*)d_in[2];
  const float* enc_w2 = (const float*)d_in[3];
  const float* enc_b2 = (const float*)d_in[4];
  const float* conv_w = (const float*)d_in[5];
  const float* conv_b = (const float*)d_in[6];
  const float* sigma  = (const float*)d_in[7];
  const float* dec_w1 = (const float*)d_in[8];
  const float* dec_b1 = (const float*)d_in[9];
  const float* dec_w2 = (const float*)d_in[10];
  const float* dec_b2 = (const float*)d_in[11];
  const int* node_idx = (const int*)d_in[12];
  const int* edge_idx = (const int*)d_in[13];
  const int* seed     = (const int*)d_in[14];

  char* wsb = (char*)d_ws;
  size_t off = 0;
  auto alloc = [&](size_t bytes) -> void* {
    void* p = wsb + off;
    off = (off + bytes + 255) & ~(size_t)255;
    return p;
  };
  float* y        = (float*)alloc((size_t)N_NODES * 64 * 4);
  float* e        = (float*)alloc((size_t)N_EDGES * 64 * 4);
  int* edge_cnt   = (int*)alloc((size_t)N_EDGES * 4);
  int* node_cnt   = (int*)alloc((size_t)N_NODES * 4);
  int* edge_start = (int*)alloc((size_t)N_EDGES * 4);
  int* node_start = (int*)alloc((size_t)N_NODES * 4);
  int* edge_fill  = (int*)alloc((size_t)N_EDGES * 4);
  int* node_fill  = (int*)alloc((size_t)N_NODES * 4);
  int* edge_mem   = (int*)alloc((size_t)NNZV * 4);
  int* node_mem   = (int*)alloc((size_t)NNZV * 4);
  float* edinv    = (float*)alloc((size_t)N_EDGES * 4);
  float* ndinv    = (float*)alloc((size_t)N_NODES * 4);
  unsigned* keys  = (unsigned*)alloc(2 * STEPS * 4);
  int* ebsum      = (int*)alloc(256 * 4);
  int* nbsum      = (int*)alloc(256 * 4);

  const int EB = (N_EDGES + 1023) / 1024;   // 13
  const int NB = (N_NODES + 1023) / 1024;   // 49

  dim3 b256(256);
  hipLaunchKernelGGL(k_keys, dim3(1), dim3(64), 0, stream, seed, keys);
  hipLaunchKernelGGL(k_zero, dim3((N_EDGES + 255) / 256), b256, 0, stream, edge_cnt, N_EDGES);
  hipLaunchKernelGGL(k_zero, dim3((N_NODES + 255) / 256), b256, 0, stream, node_cnt, N_NODES);
  hipLaunchKernelGGL(k_hist, dim3((NNZV + 255) / 256), b256, 0, stream,
                     node_idx, edge_idx, edge_cnt, node_cnt);
  hipLaunchKernelGGL(k_reduce, dim3(EB), b256, 0, stream, edge_cnt, N_EDGES, ebsum);
  hipLaunchKernelGGL(k_reduce, dim3(NB), b256, 0, stream, node_cnt, N_NODES, nbsum);
  hipLaunchKernelGGL(k_scanb, dim3(1), b256, 0, stream, ebsum, EB);
  hipLaunchKernelGGL(k_scanb, dim3(1), b256, 0, stream, nbsum, NB);
  hipLaunchKernelGGL(k_scatter, dim3(EB), b256, 0, stream,
                     edge_cnt, ebsum, N_EDGES, edge_start, edge_fill, edinv);
  hipLaunchKernelGGL(k_scatter, dim3(NB), b256, 0, stream,
                     node_cnt, nbsum, N_NODES, node_start, node_fill, ndinv);
  hipLaunchKernelGGL(k_fill, dim3((NNZV + 255) / 256), b256, 0, stream,
                     node_idx, edge_idx, edge_start, node_start,
                     edge_fill, node_fill, edge_mem, node_mem);
  hipLaunchKernelGGL(k_encoder, dim3(1024), b256, 0, stream,
                     x, enc_w1, enc_b1, enc_w2, enc_b2, y);
  for (int s = 0; s < STEPS; ++s) {
    hipLaunchKernelGGL(k_edge, dim3(2048), b256, 0, stream,
                       y, e, edge_start, edge_cnt, edge_mem, edinv, conv_w);
    hipLaunchKernelGGL(k_node, dim3(2048), b256, 0, stream,
                       e, y, node_start, node_cnt, node_mem, ndinv,
                       conv_b, sigma, keys, s);
  }
  hipLaunchKernelGGL(k_decoder, dim3(1024), b256, 0, stream,
                     y, dec_w1, dec_b1, dec_w2, dec_b2, (float*)d_out);
}